// Round 4
// baseline (394.658 us; speedup 1.0000x reference)
//
#include <hip/hip_runtime.h>

// SimAttn: out = softmax(1000*softmax(QK^T/sqrt(dk))) @ V, fp32 I/O.
// Two-pass flash, 32x32x16 f16 MFMA, wave = (q-half, k-half) specialist:
//   QK: A = K (LDS, 16-granule XOR swizzle), B = Q (regs) -> S^T, q on lanes.
//   pass 1: row max m + l8 = sum exp(s*SCALE-8); merge across g-halves
//           (shfl_xor 32) and across k-half waves (small LDS).
//   pass 2: identical scores -> w = exp(u*(p-pm)) in regs; w -> PV A-frag via
//           ONE shfl_xor(32) + cndmask (no LDS round-trip); PV over the
//           wave's 32-k stripe; partial O reduced across k-half waves at the
//           end through a 32KB LDS overlay (kf/vts dead by then).

typedef __attribute__((ext_vector_type(4))) float f32x4;
typedef __attribute__((ext_vector_type(16))) float f32x16;
typedef __attribute__((ext_vector_type(8))) _Float16 h16x8;
typedef __attribute__((ext_vector_type(4))) _Float16 h16x4;
typedef __attribute__((ext_vector_type(8))) short s16x8;
typedef __attribute__((ext_vector_type(4))) short s16x4;
typedef __attribute__((ext_vector_type(4))) unsigned int u32x4;

#define NB 4
#define T_ 2048
#define D_ 1024
#define NH 8
#define DK 128
#define BQ 64
#define KB 64
#define NKC (T_ / KB)
#define SCALE 0.08838834764831845f  // 1/sqrt(128)
#define MOFF 8.0f                   // fixed stabilizer, > max possible score

__device__ __forceinline__ unsigned int pk2(float a, float b) {
  return __builtin_bit_cast(unsigned int, __builtin_amdgcn_cvt_pkrtz(a, b));
}
#define H8(p) __builtin_bit_cast(h16x8, *(const s16x8*)(p))

__global__ __launch_bounds__(256, 3) void simattn_v4(
    const float* __restrict__ Qg, const float* __restrict__ Kg,
    const float* __restrict__ Vg, float* __restrict__ Og) {
  // smem map: [0,16K) kf[64][128]; [16K,32K) vts[128][64];
  //           [32K,+512) statm[4][32]; [+512,+1K) statl[4][32].
  // End-of-kernel overlay: [0,32K) = ybuf[2][64][64] f32.
  __shared__ __align__(16) char smem[33792];
  auto* kf   = (unsigned short(*)[DK])(smem);
  auto* vts  = (unsigned short(*)[KB])(smem + 16384);
  float* statm = (float*)(smem + 32768);
  float* statl = (float*)(smem + 32768 + 512);
  float* ybuf  = (float*)(smem);

  const int tid  = threadIdx.x;
  const int wid  = tid >> 6;
  const int lane = tid & 63;
  const int c    = lane & 31;     // q-col (QK) / d-col (PV B) / C-D col
  const int g    = lane >> 5;     // half-wave: k-slot group
  const bool hi  = (g != 0);
  const int qt   = wid & 1;       // q-half (32 rows)
  const int kt   = wid >> 1;      // k-half of each 64-chunk

  const int blk  = blockIdx.x;
  const int qblk = blk & (T_ / BQ - 1);
  const int h    = (blk >> 5) & (NH - 1);
  const int b    = blk >> 8;
  const int q0   = qblk * BQ;
  const size_t bh = (size_t)b * (T_ * D_) + (size_t)h * DK;

  const int krow = kt * 32 + c;   // this lane's k-row within a chunk (QK A)

  // ---- Q B-frags (f16): lane holds Q[d = step*16 + g*8 + i][q = qt*32+c] ---
  h16x8 qB[8];
  {
    const float* qp = Qg + bh + (size_t)(q0 + qt * 32 + c) * D_;
#pragma unroll
    for (int step = 0; step < 8; ++step) {
      const int d0 = step * 16 + g * 8;
      f32x4 x0 = *(const f32x4*)(qp + d0);
      f32x4 x1 = *(const f32x4*)(qp + d0 + 4);
#pragma unroll
      for (int i = 0; i < 4; ++i) {
        qB[step][i]     = (_Float16)x0[i];
        qB[step][i + 4] = (_Float16)x1[i];
      }
    }
  }

  // K staging: [key][d] f16, 16B-granule XOR by (row&15): conflict-free.
  auto stageK = [&](int kc) {
    const float* kp = Kg + bh + (size_t)kc * KB * D_;
#pragma unroll
    for (int p = 0; p < 8; ++p) {
      const int j = tid + p * 256;
      const int row = j >> 5, c4 = j & 31;
      f32x4 v = *(const f32x4*)(kp + (size_t)row * D_ + c4 * 4);
      h16x4 hv;
#pragma unroll
      for (int i = 0; i < 4; ++i) hv[i] = (_Float16)v[i];
      const int e = ((((c4 >> 1) ^ (row & 15)) << 3) | ((c4 & 1) << 2));
      *(s16x4*)&kf[row][e] = __builtin_bit_cast(s16x4, hv);
    }
  };

  // QK: 8 K-steps over d; st[reg] = S[k = krow... row=(reg&3)+8(reg>>2)+4g][q=c]
  auto qkT = [&](f32x16& st) {
#pragma unroll
    for (int i = 0; i < 16; ++i) st[i] = 0.f;
#pragma unroll
    for (int step = 0; step < 8; ++step) {
      h16x8 af = H8(&kf[krow][(((step * 2 + g) ^ (krow & 15)) << 3)]);
      st = __builtin_amdgcn_mfma_f32_32x32x16_f16(af, qB[step], st, 0, 0, 0);
    }
  };

  // ---- pass 1: stats ------------------------------------------------------
  float msc = -3.0e38f, l8 = 0.f;
  for (int kc = 0; kc < NKC; ++kc) {
    __syncthreads();
    stageK(kc);
    __syncthreads();
    f32x16 st;
    qkT(st);
#pragma unroll
    for (int r = 0; r < 16; ++r) {
      const float s = st[r];
      msc = fmaxf(msc, s);
      l8 += __expf(fmaf(s, SCALE, -MOFF));
    }
  }
  msc = fmaxf(msc, __shfl_xor(msc, 32));
  l8 += __shfl_xor(l8, 32);
  statm[wid * 32 + c] = msc;
  statl[wid * 32 + c] = l8;
  __syncthreads();
  {
    const int pw = wid ^ 2;  // partner k-half wave, same q-half
    msc = fmaxf(msc, statm[pw * 32 + c]);
    l8 += statl[pw * 32 + c];
  }
  const float pm  = __expf(fmaf(msc, SCALE, -MOFF));  // exact max_k p_k
  const float u_  = 1000.0f / l8;
  const float mcu = -u_ * pm;

  // ---- pass 2: scores -> w (regs) -> PV over own 32-k stripe ---------------
  f32x16 y[4];
#pragma unroll
  for (int dt = 0; dt < 4; ++dt)
#pragma unroll
    for (int i = 0; i < 16; ++i) y[dt][i] = 0.f;
  float Wl = 0.f;
  const int dv  = tid & 127;
  const int kg0 = tid >> 7;

  for (int kc = 0; kc < NKC; ++kc) {
    __syncthreads();
    stageK(kc);
    {
      // V^T staging: coalesced d-major gathers, b128 store per octet slot.
      const float* vp = Vg + bh + (size_t)kc * KB * D_ + dv;
#pragma unroll
      for (int i = 0; i < 4; ++i) {
        const int kg = kg0 + 2 * i;
        const float* vq = vp + (size_t)kg * 8 * D_;
        const float x0 = vq[0],      x1 = vq[D_],     x2 = vq[2 * D_], x3 = vq[3 * D_];
        const float x4 = vq[4 * D_], x5 = vq[5 * D_], x6 = vq[6 * D_], x7 = vq[7 * D_];
        u32x4 pv;
        pv[0] = pk2(x0, x1); pv[1] = pk2(x2, x3);
        pv[2] = pk2(x4, x5); pv[3] = pk2(x6, x7);
        *(u32x4*)&vts[dv][(kg ^ (dv & 7)) * 8] = pv;
      }
    }
    __syncthreads();

    f32x16 st;
    qkT(st);  // bitwise-identical to pass 1

#pragma unroll
    for (int ks = 0; ks < 2; ++ks) {
      // w for regs [8ks, 8ks+8): k_local = r4 + 4g + 8*(2ks+jj)
      unsigned Dj[2][2];
#pragma unroll
      for (int jj = 0; jj < 2; ++jj) {
        float w4[4];
#pragma unroll
        for (int r4 = 0; r4 < 4; ++r4) {
          const float pp = __expf(fmaf(st[ks * 8 + jj * 4 + r4], SCALE, -MOFF));
          const float w  = __expf(fmaf(pp, u_, mcu));
          Wl += w;
          w4[r4] = w;
        }
        Dj[jj][0] = pk2(w4[0], w4[1]);
        Dj[jj][1] = pk2(w4[2], w4[3]);
      }
      // C/D -> A-frag: one half-swap + selects. Lane g=0 keeps Dj[0] (k 16ks+0..3)
      // and takes partner's Dj[0] (k 16ks+4..7); lane g=1 takes partner's Dj[1]
      // (k 16ks+8..11) and keeps Dj[1] (k 16ks+12..15).
      const unsigned r0 = (unsigned)__shfl_xor((int)(hi ? Dj[0][0] : Dj[1][0]), 32);
      const unsigned r1 = (unsigned)__shfl_xor((int)(hi ? Dj[0][1] : Dj[1][1]), 32);
      u32x4 aw;
      aw[0] = hi ? r0 : Dj[0][0];
      aw[1] = hi ? r1 : Dj[0][1];
      aw[2] = hi ? Dj[1][0] : r0;
      aw[3] = hi ? Dj[1][1] : r1;
      const h16x8 af = __builtin_bit_cast(h16x8, aw);
      const int kob = kt * 4 + ks * 2 + g;  // k-octet index of this lane's B reads
#pragma unroll
      for (int dt = 0; dt < 4; ++dt) {
        const int d = dt * 32 + c;
        h16x8 vf = H8(&vts[d][(kob ^ (d & 7)) * 8]);
        y[dt] = __builtin_amdgcn_mfma_f32_32x32x16_f16(af, vf, y[dt], 0, 0, 0);
      }
    }
  }

  // ---- cross-wave (k-half) reduction + normalize + store -------------------
  Wl += __shfl_xor(Wl, 32);
  __syncthreads();  // all waves done reading kf/vts -> safe to overlay
  if (kt == 1) {
    float* p = ybuf + qt * 4096 + lane;
#pragma unroll
    for (int dt = 0; dt < 4; ++dt)
#pragma unroll
      for (int r = 0; r < 16; ++r) p[(dt * 16 + r) * 64] = y[dt][r];
    statm[qt * 32 + c] = Wl;
  }
  __syncthreads();
  if (kt == 0) {
    const float* p = ybuf + qt * 4096 + lane;
#pragma unroll
    for (int dt = 0; dt < 4; ++dt)
#pragma unroll
      for (int r = 0; r < 16; ++r) y[dt][r] += p[(dt * 16 + r) * 64];
    const float winv = 1.0f / (Wl + statm[qt * 32 + c]);  // valid for q=c
    float* ob = Og + bh + (size_t)(q0 + qt * 32) * D_;
#pragma unroll
    for (int r = 0; r < 16; ++r) {
      const int qrow = (r & 3) + 8 * (r >> 2) + 4 * g;   // C/D row (verified map)
      const float wv = __shfl(winv, qrow);
#pragma unroll
      for (int dt = 0; dt < 4; ++dt) {
        ob[(size_t)qrow * D_ + dt * 32 + c] = y[dt][r] * wv;
      }
    }
  }
}

extern "C" void kernel_launch(void* const* d_in, const int* in_sizes, int n_in,
                              void* d_out, int out_size, void* d_ws, size_t ws_size,
                              hipStream_t stream) {
  (void)in_sizes; (void)n_in; (void)d_ws; (void)ws_size; (void)out_size;
  const float* Q = (const float*)d_in[0];
  const float* K = (const float*)d_in[1];
  const float* V = (const float*)d_in[2];
  float* O = (float*)d_out;
  dim3 grid(NB * NH * (T_ / BQ));  // 1024 workgroups, 4 waves each
  simattn_v4<<<grid, 256, 0, stream>>>(Q, K, V, O);
}

// Round 5
// 296.597 us; speedup vs baseline: 1.3306x; 1.3306x over previous
//
#include <hip/hip_runtime.h>

// SimAttn: out = softmax(1000*softmax(QK^T/sqrt(dk))) @ V, fp32 I/O.
// R3 structure (two-pass flash, 16x16x32 f16 MFMA, swapped QK^T) plus:
//   - T14 async-STAGE: K global->reg prefetch one chunk ahead (both passes);
//     V gathers issued before K ds_writes so their latency overlaps.
//   - T1 XCD-chunked blockIdx swizzle (1024 blocks = 8 XCDs x 128).
// pass 1: f16 QK^T -> row max m, l8 = sum exp(s*SCALE-8)  (fixed stabilizer)
// pass 2: bitwise-identical scores, p=exp(s*SCALE-8), w=exp(u*(p-pm)),
//         u=1000/l8, pm=exp(m*SCALE-8) -> w<=~1; PV f16 MFMA on w;
//         normalize by sum(w) at the end.

typedef __attribute__((ext_vector_type(4))) float f32x4;
typedef __attribute__((ext_vector_type(8))) _Float16 h16x8;
typedef __attribute__((ext_vector_type(4))) _Float16 h16x4;
typedef __attribute__((ext_vector_type(8))) short s16x8;
typedef __attribute__((ext_vector_type(4))) short s16x4;
typedef __attribute__((ext_vector_type(2))) unsigned int u32x2;
typedef __attribute__((ext_vector_type(4))) unsigned int u32x4;

#define NB 4
#define T_ 2048
#define D_ 1024
#define NH 8
#define DK 128
#define BQ 64
#define KB 64
#define NKC (T_ / KB)
#define NWG (NB * NH * (T_ / BQ))  // 1024
#define SCALE 0.08838834764831845f  // 1/sqrt(128)
#define MOFF 8.0f                   // fixed stabilizer, > max possible score

__device__ __forceinline__ unsigned int pk2(float a, float b) {
  return __builtin_bit_cast(unsigned int, __builtin_amdgcn_cvt_pkrtz(a, b));
}
#define H8(p) __builtin_bit_cast(h16x8, *(const s16x8*)(p))

__global__ __launch_bounds__(256, 4) void simattn_v5(
    const float* __restrict__ Qg, const float* __restrict__ Kg,
    const float* __restrict__ Vg, float* __restrict__ Og) {
  __shared__ __align__(16) unsigned short kf[KB][DK];    // 16 KB
  __shared__ __align__(16) unsigned short vts[DK][KB];   // 16 KB (V^T, slotted)
  __shared__ __align__(16) unsigned int   wls[4][16][32];//  8 KB (w, dword-packed)

  const int tid  = threadIdx.x;
  const int wid  = tid >> 6;
  const int lane = tid & 63;
  const int lr   = lane & 15;   // q-row (B-col of swapped QK; A-row of PV)
  const int lg   = lane >> 4;   // k-slot group

  // XCD-chunked swizzle: consecutive 128 blocks land on one XCD.
  const int blk  = (blockIdx.x & 7) * (NWG >> 3) + (blockIdx.x >> 3);
  const int qblk = blk & (T_ / BQ - 1);
  const int h    = (blk >> 5) & (NH - 1);
  const int b    = blk >> 8;
  const int q0   = qblk * BQ;
  const size_t bh = (size_t)b * (T_ * D_) + (size_t)h * DK;

  // ---- Q fragments (f16, RNE), kept in registers ---------------------------
  h16x8 qf[4];
  {
    const float* qp = Qg + bh + (size_t)(q0 + wid * 16 + lr) * D_;
#pragma unroll
    for (int s = 0; s < 4; ++s) {
      const int d0 = s * 32 + lg * 8;
      f32x4 x0 = *(const f32x4*)(qp + d0);
      f32x4 x1 = *(const f32x4*)(qp + d0 + 4);
#pragma unroll
      for (int i = 0; i < 4; ++i) {
        qf[s][i]     = (_Float16)x0[i];
        qf[s][i + 4] = (_Float16)x1[i];
      }
    }
  }

  // ---- K staging: prefetched global->reg (T14), then reg->LDS --------------
  f32x4 kpre[8];
  auto loadK = [&](int kc) {
    const float* kp = Kg + bh + (size_t)kc * KB * D_;
#pragma unroll
    for (int p = 0; p < 8; ++p) {
      const int j = tid + p * 256;
      kpre[p] = *(const f32x4*)(kp + (size_t)(j >> 5) * D_ + (j & 31) * 4);
    }
  };
  auto writeK = [&]() {
#pragma unroll
    for (int p = 0; p < 8; ++p) {
      const int j = tid + p * 256;
      const int row = j >> 5, c4 = j & 31;
      h16x4 hv;
#pragma unroll
      for (int i = 0; i < 4; ++i) hv[i] = (_Float16)kpre[p][i];  // RNE
      const int e = (c4 * 4) ^ ((row & 7) << 3);
      *(s16x4*)&kf[row][e] = __builtin_bit_cast(s16x4, hv);
    }
  };

  // Swapped QK^T: st[nt][r] = S[k = nt*16 + lg*4 + r][q = lr]
  auto qkT = [&](f32x4* st) {
#pragma unroll
    for (int nt = 0; nt < 4; ++nt) st[nt] = (f32x4){0.f, 0.f, 0.f, 0.f};
#pragma unroll
    for (int s = 0; s < 4; ++s) {
#pragma unroll
      for (int nt = 0; nt < 4; ++nt) {
        const int kr = nt * 16 + lr;
        const int e = (s * 32 + lg * 8) ^ ((kr & 7) << 3);
        st[nt] = __builtin_amdgcn_mfma_f32_16x16x32_f16(H8(&kf[kr][e]), qf[s],
                                                        st[nt], 0, 0, 0);
      }
    }
  };

  // ---- pass 1: per-q max (raw units) + l8 = sum exp(s*SCALE - 8) -----------
  float msc = -3.0e38f, l8 = 0.f;
  loadK(0);
  for (int kc = 0; kc < NKC; ++kc) {
    __syncthreads();          // previous tile's reads complete
    writeK();                 // prefetched chunk kc -> LDS
    if (kc + 1 < NKC) loadK(kc + 1);  // in flight across the compute phase
    __syncthreads();
    f32x4 st[4];
    qkT(st);
#pragma unroll
    for (int nt = 0; nt < 4; ++nt) {
#pragma unroll
      for (int r = 0; r < 4; ++r) {
        const float s = st[nt][r];
        msc = fmaxf(msc, s);
        l8 += __expf(fmaf(s, SCALE, -MOFF));
      }
    }
  }
  // merge across the 4 lane-groups (this lane's q = lr)
  msc = fmaxf(msc, __shfl_xor(msc, 16));
  msc = fmaxf(msc, __shfl_xor(msc, 32));
  l8 += __shfl_xor(l8, 16);
  l8 += __shfl_xor(l8, 32);
  const float pm  = __expf(fmaf(msc, SCALE, -MOFF));  // exact max_k p_k
  const float u_  = 1000.0f / l8;
  const float mcu = -u_ * pm;

  // ---- pass 2: scores -> weights -> PV -------------------------------------
  f32x4 y[8];
#pragma unroll
  for (int dt = 0; dt < 8; ++dt) y[dt] = (f32x4){0.f, 0.f, 0.f, 0.f};
  float Wl = 0.f;
  const int dv  = tid & 127;  // V^T staging: this thread's d-row
  const int kg0 = tid >> 7;

  loadK(0);
  for (int kc = 0; kc < NKC; ++kc) {
    __syncthreads();
    // V gathers issued first: latency overlaps writeK/loadK below.
    float vx[32];
    {
      const float* vp = Vg + bh + (size_t)kc * KB * D_ + dv;
#pragma unroll
      for (int i = 0; i < 4; ++i) {
        const float* vq = vp + (size_t)(kg0 + 2 * i) * 8 * D_;
#pragma unroll
        for (int j = 0; j < 8; ++j) vx[i * 8 + j] = vq[(size_t)j * D_];
      }
    }
    writeK();                 // prefetched K chunk kc -> LDS
    if (kc + 1 < NKC) loadK(kc + 1);
#pragma unroll
    for (int i = 0; i < 4; ++i) {  // pack + store V^T
      u32x4 pv;
      pv[0] = pk2(vx[i * 8 + 0], vx[i * 8 + 1]);
      pv[1] = pk2(vx[i * 8 + 2], vx[i * 8 + 3]);
      pv[2] = pk2(vx[i * 8 + 4], vx[i * 8 + 5]);
      pv[3] = pk2(vx[i * 8 + 6], vx[i * 8 + 7]);
      *(u32x4*)&vts[dv][((kg0 + 2 * i) ^ (dv & 7)) * 8] = pv;
    }
    __syncthreads();

    f32x4 st[4];
    qkT(st);  // bitwise-identical to pass 1

    // weights for q = lr, k = nt*16 + lg*4 + r; pack adjacent-k pairs.
#pragma unroll
    for (int nt = 0; nt < 4; ++nt) {
      float w[4];
#pragma unroll
      for (int r = 0; r < 4; ++r) {
        const float pp = __expf(fmaf(st[nt][r], SCALE, -MOFF));
        w[r] = __expf(fmaf(pp, u_, mcu));
      }
      Wl += (w[0] + w[1]) + (w[2] + w[3]);
      u32x2 pk;
      pk[0] = pk2(w[0], w[1]);
      pk[1] = pk2(w[2], w[3]);
      *(u32x2*)&wls[wid][lr][(nt * 8 + lg * 2) ^ ((lr & 7) << 2)] = pk;
    }

    // PV: A = w rows (same-wave LDS round-trip), B = slotted V^T.
#pragma unroll
    for (int ks = 0; ks < 2; ++ks) {
      h16x8 af = H8((const unsigned short*)&wls[wid][lr]
                    [(ks * 16 + lg * 4) ^ ((lr & 7) << 2)]);
#pragma unroll
      for (int dt = 0; dt < 8; ++dt) {
        const int d = dt * 16 + lr;
        h16x8 vf = H8(&vts[d][((ks * 4 + lg) ^ (d & 7)) * 8]);
        y[dt] = __builtin_amdgcn_mfma_f32_16x16x32_f16(af, vf, y[dt], 0, 0, 0);
      }
    }
  }

  // ---- normalize and store -------------------------------------------------
  Wl += __shfl_xor(Wl, 16);
  Wl += __shfl_xor(Wl, 32);
  const float winv = 1.0f / Wl;  // valid for q = lr

  float* op = Og + bh + (size_t)(q0 + wid * 16) * D_;
#pragma unroll
  for (int r = 0; r < 4; ++r) {
    const float wv = __shfl(winv, lg * 4 + r);  // fetch W for q-row lg*4+r
#pragma unroll
    for (int dt = 0; dt < 8; ++dt) {
      op[(size_t)(lg * 4 + r) * D_ + dt * 16 + lr] = y[dt][r] * wv;
    }
  }
}

extern "C" void kernel_launch(void* const* d_in, const int* in_sizes, int n_in,
                              void* d_out, int out_size, void* d_ws, size_t ws_size,
                              hipStream_t stream) {
  (void)in_sizes; (void)n_in; (void)d_ws; (void)ws_size; (void)out_size;
  const float* Q = (const float*)d_in[0];
  const float* K = (const float*)d_in[1];
  const float* V = (const float*)d_in[2];
  float* O = (float*)d_out;
  dim3 grid(NWG);  // 1024 workgroups, 4 waves each
  simattn_v5<<<grid, 256, 0, stream>>>(Q, K, V, O);
}

// Round 6
// 172.362 us; speedup vs baseline: 2.2897x; 1.7208x over previous
//
#include <hip/hip_runtime.h>

// SimAttn: out = softmax(1000*softmax(QK^T/sqrt(dk))) @ V, fp32 I/O.
// v6: pre-convert K->f16 [bh][k][d] and V->f16 transposed [bh][d][k] into d_ws
// (two tiny pre-kernels), then the two-pass flash main kernel stages K/V^T
// tiles with global_load_lds width-16 (linear LDS dest, swizzle folded into
// per-lane global source), KB=32 chunks, double-buffered, ONE barrier/chunk.
// Math identical to R3: pass1 f16 QK^T -> (m, l8); pass2 identical scores ->
// w = exp(u*(p-pm)) <= 1 -> LDS w-tile -> PV f16 MFMA -> normalize by sum(w).
// Falls back to the R3 kernel if ws_size < 33.6 MB.

typedef __attribute__((ext_vector_type(4))) float f32x4;
typedef __attribute__((ext_vector_type(8))) _Float16 h16x8;
typedef __attribute__((ext_vector_type(4))) _Float16 h16x4;
typedef __attribute__((ext_vector_type(8))) short s16x8;
typedef __attribute__((ext_vector_type(4))) short s16x4;
typedef __attribute__((ext_vector_type(2))) unsigned int u32x2;
typedef __attribute__((ext_vector_type(4))) unsigned int u32x4;

#define NB 4
#define T_ 2048
#define D_ 1024
#define NH 8
#define DK 128
#define BQ 64
#define NWG (NB * NH * (T_ / BQ))  // 1024
#define KB2 32
#define NKC2 (T_ / KB2)            // 64
#define SCALE 0.08838834764831845f // 1/sqrt(128)
#define MOFF 8.0f                  // fixed stabilizer, > max possible score

__device__ __forceinline__ unsigned int pk2(float a, float b) {
  return __builtin_bit_cast(unsigned int, __builtin_amdgcn_cvt_pkrtz(a, b));
}
#define H8(p) __builtin_bit_cast(h16x8, *(const s16x8*)(p))

__device__ __forceinline__ void gload16(const unsigned short* g, unsigned short* l) {
  __builtin_amdgcn_global_load_lds(
      (const __attribute__((address_space(1))) void*)g,
      (__attribute__((address_space(3))) void*)l, 16, 0, 0);
}

// ---- pre-kernel 1: K fp32 [b][k][h*128+d] -> f16 K16[(b*8+h)][k][d] --------
__global__ __launch_bounds__(256) void cvtK16(const float* __restrict__ Kg,
                                              unsigned short* __restrict__ K16) {
  const int t = threadIdx.x;
#pragma unroll
  for (int i = 0; i < 4; ++i) {
    const unsigned gid = blockIdx.x * 1024u + i * 256u + t;
    const unsigned bhk = gid >> 4, dg = gid & 15u;
    const unsigned b = bhk >> 14, rem = bhk & 16383u;
    const unsigned h = rem >> 11, k = rem & 2047u;
    const float* s = Kg + ((size_t)b * T_ + k) * D_ + h * DK + dg * 8;
    f32x4 x0 = *(const f32x4*)s, x1 = *(const f32x4*)(s + 4);
    h16x8 hv;
#pragma unroll
    for (int j = 0; j < 4; ++j) { hv[j] = (_Float16)x0[j]; hv[j + 4] = (_Float16)x1[j]; }
    *(u32x4*)(K16 + (size_t)gid * 8) = __builtin_bit_cast(u32x4, hv);
  }
}

// ---- pre-kernel 2: V fp32 -> f16 transposed V16t[(b*8+h)][d][k] ------------
__global__ __launch_bounds__(256) void trV16(const float* __restrict__ Vg,
                                             unsigned short* __restrict__ V16t) {
  __shared__ float vt[64][129];
  const int t = threadIdx.x;
  const int bh = blockIdx.x >> 5;
  const int kc = blockIdx.x & 31;
  const int b = bh >> 3, h = bh & 7;
  const float* src = Vg + ((size_t)b * T_ + kc * 64) * D_ + h * DK;
#pragma unroll
  for (int p = 0; p < 8; ++p) {
    const int j = t + p * 256;
    const int row = j >> 5, c4 = j & 31;
    f32x4 v = *(const f32x4*)(src + (size_t)row * D_ + c4 * 4);
#pragma unroll
    for (int i = 0; i < 4; ++i) vt[row][c4 * 4 + i] = v[i];
  }
  __syncthreads();
  unsigned short* dst = V16t + (size_t)bh * DK * T_ + (size_t)kc * 64;
#pragma unroll
  for (int i = 0; i < 4; ++i) {
    const int gg = t + i * 256;
    const int d = gg >> 3, kg = gg & 7;
    u32x4 pv;
#pragma unroll
    for (int jj = 0; jj < 4; ++jj)
      pv[jj] = pk2(vt[kg * 8 + 2 * jj][d], vt[kg * 8 + 2 * jj + 1][d]);
    *(u32x4*)(dst + (size_t)d * T_ + kg * 8) = pv;
  }
}

// ---- main kernel -----------------------------------------------------------
__global__ __launch_bounds__(256, 4) void simattn_v6(
    const float* __restrict__ Qg, const unsigned short* __restrict__ K16,
    const unsigned short* __restrict__ V16t, float* __restrict__ Og) {
  __shared__ __align__(16) unsigned short kf[2][KB2 * DK];   // 16 KB
  __shared__ __align__(16) unsigned short vts[2][DK * KB2];  // 16 KB
  __shared__ __align__(16) unsigned int   wls[4][256];       //  4 KB

  const int tid  = threadIdx.x;
  const int wid  = tid >> 6;
  const int lane = tid & 63;
  const int lr   = lane & 15;
  const int lg   = lane >> 4;

  // XCD-chunked swizzle (1024 % 8 == 0 -> simple bijection)
  const int blk  = (blockIdx.x & 7) * (NWG >> 3) + (blockIdx.x >> 3);
  const int qblk = blk & (T_ / BQ - 1);
  const int h    = (blk >> 5) & (NH - 1);
  const int b    = blk >> 8;
  const int q0   = qblk * BQ;
  const size_t bh  = (size_t)b * (T_ * D_) + (size_t)h * DK;  // fp32 panels
  const int    bhp = b * NH + h;                              // f16 panel idx
  const unsigned short* kp16 = K16 + (size_t)bhp * (T_ * DK);
  const unsigned short* vp16 = V16t + (size_t)bhp * (DK * T_);

  // ---- Q fragments (f16, RNE), kept in registers ---------------------------
  h16x8 qf[4];
  {
    const float* qp = Qg + bh + (size_t)(q0 + wid * 16 + lr) * D_;
#pragma unroll
    for (int s = 0; s < 4; ++s) {
      const int d0 = s * 32 + lg * 8;
      f32x4 x0 = *(const f32x4*)(qp + d0);
      f32x4 x1 = *(const f32x4*)(qp + d0 + 4);
#pragma unroll
      for (int i = 0; i < 4; ++i) {
        qf[s][i]     = (_Float16)x0[i];
        qf[s][i + 4] = (_Float16)x1[i];
      }
    }
  }

  // ---- per-lane staging source offsets (elements), chunk-invariant ---------
  // K tile: 32 rows x 16 granules(8 f16); LDS granule (r,g) <- global (r, g^(r&7))
  int koffs[2], voffs[2];
  const int kdst0 = wid * 1024;  // elements: 2 instrs x 512
#pragma unroll
  for (int i = 0; i < 2; ++i) {
    const int id = wid * 2 + i;
    {
      const int r = id * 4 + (lane >> 4), gL = lane & 15;
      koffs[i] = r * DK + ((gL ^ (r & 7)) * 8);
    }
    {
      const int d = id * 16 + (lane >> 2), s = lane & 3;
      voffs[i] = d * T_ + ((s ^ ((d >> 1) & 3)) * 8);
    }
  }
  auto stK = [&](int kc, int buf) {
    const unsigned short* s0 = kp16 + (size_t)kc * (KB2 * DK);
    gload16(s0 + koffs[0], &kf[buf][kdst0]);
    gload16(s0 + koffs[1], &kf[buf][kdst0 + 512]);
  };
  auto stV = [&](int kc, int buf) {
    const unsigned short* s0 = vp16 + kc * KB2;
    gload16(s0 + voffs[0], &vts[buf][kdst0]);
    gload16(s0 + voffs[1], &vts[buf][kdst0 + 512]);
  };

  // Swapped QK^T (KB2=32): st[nt][r] = S[k = nt*16 + lg*4 + r][q = lr]
  auto qkT = [&](int buf, f32x4* st) {
    st[0] = (f32x4){0.f, 0.f, 0.f, 0.f};
    st[1] = (f32x4){0.f, 0.f, 0.f, 0.f};
#pragma unroll
    for (int s = 0; s < 4; ++s) {
#pragma unroll
      for (int nt = 0; nt < 2; ++nt) {
        const int kr = nt * 16 + lr;
        const int eg = ((4 * s + lg) ^ (kr & 7)) * 8;
        st[nt] = __builtin_amdgcn_mfma_f32_16x16x32_f16(
            H8(&kf[buf][kr * DK + eg]), qf[s], st[nt], 0, 0, 0);
      }
    }
  };

  // ---- pass 1: per-q max + l8 = sum exp(s*SCALE - 8) -----------------------
  float msc = -3.0e38f, l8 = 0.f;
  stK(0, 0);
  __syncthreads();
  for (int kc = 0; kc < NKC2; ++kc) {
    if (kc + 1 < NKC2) stK(kc + 1, (kc + 1) & 1);
    f32x4 st[2];
    qkT(kc & 1, st);
#pragma unroll
    for (int nt = 0; nt < 2; ++nt) {
#pragma unroll
      for (int r = 0; r < 4; ++r) {
        const float s = st[nt][r];
        msc = fmaxf(msc, s);
        l8 += __expf(fmaf(s, SCALE, -MOFF));
      }
    }
    __syncthreads();  // drains vmcnt -> next tile ready; retires this tile's reads
  }
  msc = fmaxf(msc, __shfl_xor(msc, 16));
  msc = fmaxf(msc, __shfl_xor(msc, 32));
  l8 += __shfl_xor(l8, 16);
  l8 += __shfl_xor(l8, 32);
  const float pm  = __expf(fmaf(msc, SCALE, -MOFF));  // exact max_k p_k
  const float u_  = 1000.0f / l8;
  const float mcu = -u_ * pm;

  // ---- pass 2: scores -> weights -> PV -------------------------------------
  f32x4 y[8];
#pragma unroll
  for (int dt = 0; dt < 8; ++dt) y[dt] = (f32x4){0.f, 0.f, 0.f, 0.f};
  float Wl = 0.f;
  const int wswz = (lr >> 1) & 3;

  stK(0, 0);
  stV(0, 0);
  __syncthreads();
  for (int kc = 0; kc < NKC2; ++kc) {
    if (kc + 1 < NKC2) { stK(kc + 1, (kc + 1) & 1); stV(kc + 1, (kc + 1) & 1); }
    const int buf = kc & 1;
    f32x4 st[2];
    qkT(buf, st);  // bitwise-identical to pass 1

    // weights for q = lr, k = nt*16 + lg*4 + r; pack pairs -> swizzled w tile
#pragma unroll
    for (int nt = 0; nt < 2; ++nt) {
      float w[4];
#pragma unroll
      for (int r = 0; r < 4; ++r) {
        const float pp = __expf(fmaf(st[nt][r], SCALE, -MOFF));
        w[r] = __expf(fmaf(pp, u_, mcu));
      }
      Wl += (w[0] + w[1]) + (w[2] + w[3]);
      u32x2 pk;
      pk[0] = pk2(w[0], w[1]);
      pk[1] = pk2(w[2], w[3]);
      const int sw = (nt * 2 + (lg >> 1)) ^ wswz;
      *(u32x2*)&wls[wid][lr * 16 + sw * 4 + (lg & 1) * 2] = pk;
    }

    // PV: A = own w row (same-wave LDS round-trip), B = V^T tile.
    const h16x8 af = H8((const unsigned short*)&wls[wid][lr * 16 + (lg ^ wswz) * 4]);
#pragma unroll
    for (int dt = 0; dt < 8; ++dt) {
      const int d = dt * 16 + lr;
      const int sv = lg ^ ((d >> 1) & 3);
      y[dt] = __builtin_amdgcn_mfma_f32_16x16x32_f16(
          af, H8(&vts[buf][d * KB2 + sv * 8]), y[dt], 0, 0, 0);
    }
    __syncthreads();
  }

  // ---- normalize and store -------------------------------------------------
  Wl += __shfl_xor(Wl, 16);
  Wl += __shfl_xor(Wl, 32);
  const float winv = 1.0f / Wl;  // valid for q = lr

  float* op = Og + bh + (size_t)(q0 + wid * 16) * D_;
#pragma unroll
  for (int r = 0; r < 4; ++r) {
    const float wv = __shfl(winv, lg * 4 + r);
#pragma unroll
    for (int dt = 0; dt < 8; ++dt) {
      op[(size_t)(lg * 4 + r) * D_ + dt * 16 + lr] = y[dt][r] * wv;
    }
  }
}

// ---- fallback: R3 kernel (used when ws_size is too small) ------------------
__global__ __launch_bounds__(256, 4) void simattn_fb(
    const float* __restrict__ Qg, const float* __restrict__ Kg,
    const float* __restrict__ Vg, float* __restrict__ Og) {
  __shared__ __align__(16) unsigned short kfb[64][DK];
  __shared__ __align__(16) unsigned short vtb[DK][64];
  __shared__ __align__(16) unsigned int   wlb[4][16][32];

  const int tid  = threadIdx.x;
  const int wid  = tid >> 6;
  const int lane = tid & 63;
  const int lr   = lane & 15;
  const int lg   = lane >> 4;

  const int blk  = blockIdx.x;
  const int qblk = blk & (T_ / BQ - 1);
  const int h    = (blk >> 5) & (NH - 1);
  const int b    = blk >> 8;
  const int q0   = qblk * BQ;
  const size_t bh = (size_t)b * (T_ * D_) + (size_t)h * DK;

  h16x8 qf[4];
  {
    const float* qp = Qg + bh + (size_t)(q0 + wid * 16 + lr) * D_;
#pragma unroll
    for (int s = 0; s < 4; ++s) {
      const int d0 = s * 32 + lg * 8;
      f32x4 x0 = *(const f32x4*)(qp + d0);
      f32x4 x1 = *(const f32x4*)(qp + d0 + 4);
#pragma unroll
      for (int i = 0; i < 4; ++i) { qf[s][i] = (_Float16)x0[i]; qf[s][i+4] = (_Float16)x1[i]; }
    }
  }
  auto stageK = [&](int kc) {
    const float* kp = Kg + bh + (size_t)kc * 64 * D_;
#pragma unroll
    for (int p = 0; p < 8; ++p) {
      const int j = tid + p * 256;
      const int row = j >> 5, c4 = j & 31;
      f32x4 v = *(const f32x4*)(kp + (size_t)row * D_ + c4 * 4);
      h16x4 hv;
#pragma unroll
      for (int i = 0; i < 4; ++i) hv[i] = (_Float16)v[i];
      const int e = (c4 * 4) ^ ((row & 7) << 3);
      *(s16x4*)&kfb[row][e] = __builtin_bit_cast(s16x4, hv);
    }
  };
  auto qkT = [&](f32x4* st) {
#pragma unroll
    for (int nt = 0; nt < 4; ++nt) st[nt] = (f32x4){0.f, 0.f, 0.f, 0.f};
#pragma unroll
    for (int s = 0; s < 4; ++s) {
#pragma unroll
      for (int nt = 0; nt < 4; ++nt) {
        const int kr = nt * 16 + lr;
        const int e = (s * 32 + lg * 8) ^ ((kr & 7) << 3);
        st[nt] = __builtin_amdgcn_mfma_f32_16x16x32_f16(H8(&kfb[kr][e]), qf[s], st[nt], 0, 0, 0);
      }
    }
  };
  float msc = -3.0e38f, l8 = 0.f;
  for (int kc = 0; kc < 32; ++kc) {
    __syncthreads();
    stageK(kc);
    __syncthreads();
    f32x4 st[4];
    qkT(st);
#pragma unroll
    for (int nt = 0; nt < 4; ++nt)
#pragma unroll
      for (int r = 0; r < 4; ++r) {
        const float s = st[nt][r];
        msc = fmaxf(msc, s);
        l8 += __expf(fmaf(s, SCALE, -MOFF));
      }
  }
  msc = fmaxf(msc, __shfl_xor(msc, 16));
  msc = fmaxf(msc, __shfl_xor(msc, 32));
  l8 += __shfl_xor(l8, 16);
  l8 += __shfl_xor(l8, 32);
  const float pm  = __expf(fmaf(msc, SCALE, -MOFF));
  const float u_  = 1000.0f / l8;
  const float mcu = -u_ * pm;

  f32x4 y[8];
#pragma unroll
  for (int dt = 0; dt < 8; ++dt) y[dt] = (f32x4){0.f, 0.f, 0.f, 0.f};
  float Wl = 0.f;
  const int dv  = tid & 127;
  const int kg0 = tid >> 7;
  for (int kc = 0; kc < 32; ++kc) {
    __syncthreads();
    stageK(kc);
    {
      const float* vp = Vg + bh + (size_t)kc * 64 * D_ + dv;
#pragma unroll
      for (int i = 0; i < 4; ++i) {
        const int kg = kg0 + 2 * i;
        const float* vq = vp + (size_t)kg * 8 * D_;
        u32x4 pv;
        pv[0] = pk2(vq[0], vq[D_]);
        pv[1] = pk2(vq[2 * D_], vq[3 * D_]);
        pv[2] = pk2(vq[4 * D_], vq[5 * D_]);
        pv[3] = pk2(vq[6 * D_], vq[7 * D_]);
        *(u32x4*)&vtb[dv][(kg ^ (dv & 7)) * 8] = pv;
      }
    }
    __syncthreads();
    f32x4 st[4];
    qkT(st);
#pragma unroll
    for (int nt = 0; nt < 4; ++nt) {
      float w[4];
#pragma unroll
      for (int r = 0; r < 4; ++r) {
        const float pp = __expf(fmaf(st[nt][r], SCALE, -MOFF));
        w[r] = __expf(fmaf(pp, u_, mcu));
      }
      Wl += (w[0] + w[1]) + (w[2] + w[3]);
      u32x2 pk;
      pk[0] = pk2(w[0], w[1]);
      pk[1] = pk2(w[2], w[3]);
      *(u32x2*)&wlb[wid][lr][(nt * 8 + lg * 2) ^ ((lr & 7) << 2)] = pk;
    }
#pragma unroll
    for (int ks = 0; ks < 2; ++ks) {
      h16x8 af = H8((const unsigned short*)&wlb[wid][lr][(ks * 16 + lg * 4) ^ ((lr & 7) << 2)]);
#pragma unroll
      for (int dt = 0; dt < 8; ++dt) {
        const int d = dt * 16 + lr;
        h16x8 vf = H8(&vtb[d][((ks * 4 + lg) ^ (d & 7)) * 8]);
        y[dt] = __builtin_amdgcn_mfma_f32_16x16x32_f16(af, vf, y[dt], 0, 0, 0);
      }
    }
  }
  Wl += __shfl_xor(Wl, 16);
  Wl += __shfl_xor(Wl, 32);
  const float winv = 1.0f / Wl;
  float* op = Og + bh + (size_t)(q0 + wid * 16) * D_;
#pragma unroll
  for (int r = 0; r < 4; ++r) {
    const float wv = __shfl(winv, lg * 4 + r);
#pragma unroll
    for (int dt = 0; dt < 8; ++dt)
      op[(size_t)(lg * 4 + r) * D_ + dt * 16 + lr] = y[dt][r] * wv;
  }
}

extern "C" void kernel_launch(void* const* d_in, const int* in_sizes, int n_in,
                              void* d_out, int out_size, void* d_ws, size_t ws_size,
                              hipStream_t stream) {
  (void)in_sizes; (void)n_in; (void)out_size;
  const float* Q = (const float*)d_in[0];
  const float* K = (const float*)d_in[1];
  const float* V = (const float*)d_in[2];
  float* O = (float*)d_out;
  const size_t half = (size_t)NB * NH * T_ * DK * 2;  // 16.78 MB per tensor
  if (ws_size >= 2 * half) {
    unsigned short* K16  = (unsigned short*)d_ws;
    unsigned short* V16t = (unsigned short*)((char*)d_ws + half);
    cvtK16<<<dim3(1024), 256, 0, stream>>>(K, K16);
    trV16<<<dim3(1024), 256, 0, stream>>>(V, V16t);
    simattn_v6<<<dim3(NWG), 256, 0, stream>>>(Q, K16, V16t, O);
  } else {
    simattn_fb<<<dim3(NWG), 256, 0, stream>>>(Q, K, V, O);
  }
}